// Round 3
// baseline (226.910 us; speedup 1.0000x reference)
//
#include <hip/hip_runtime.h>

// CSConv2D: per-pixel kernel selection from a 25-entry 5x5 bank, depthwise,
// 'same' zero pad. B=8, C=96, H=W=192, fp32.
//
// R6 = R5 with the weight cache rebuilt as 100 NAMED SCALARS (macro-expanded),
// no array, no pointer access.
// Evidence: R4/R5 both report VGPR_Count=80 — a 100-float wreg[4][25] cannot
// fit, so the array was never SROA-promoted (runtime-indexed at SROA time ->
// scratch alloca; rule #20). Every FMA weight operand was a scratch/LDS
// reload: ~35 mem reads/output ~= 91us measured (R1 scaling + instr-count
// arithmetic both match). Named locals are SSA from birth: nothing to demote,
// and regalloc can't rematerialize LDS loads, so under the launch_bounds
// (384,3) cap of 168 they stay resident (~140 live).
//
// Check for next round: VGPR_Count must jump to ~140-160. If still ~80, this
// theory is wrong too.
//
// R4/R5 structure kept verbatim otherwise:
//  - Vertical register blocking: thread owns 4 output rows of one column.
//  - global_load_lds width=16 staging, LDS rows padded to 200 floats
//    (left pad 4 -> 16B-aligned dest; data in cols 4..195).
//  - 2 channels per phase, 4 LDS slabs, 12 barriers; counted
//    s_waitcnt vmcnt(8) before s_barrier (waits loads, not output stores).
//  - Halo cols / OOB rows zeroed once, persist across phases.

#define KS 5
#define NB 25
#define HALO 2
#define TH 8                     // output rows per block
#define RPT 4                    // output rows per thread
#define WID 192
#define HEI 192
#define CH 96
#define NBATCH 8
#define LPAD 4                   // left pad so row data start is 16B-aligned
#define LROW (LPAD + WID + LPAD) // 200 floats per LDS row
#define LH (TH + 2 * HALO)       // 12 staged rows
#define CSPLIT 4
#define CPB (CH / CSPLIT)        // 24 channels per block
#define NTHREADS (WID * (TH / RPT))  // 384 threads = 6 waves
#define HW ((size_t)HEI * WID)

static_assert(CPB % 2 == 0, "channel loop processes channel pairs");

__device__ __forceinline__ void async16(void* lds, const void* g) {
    // Direct global->LDS copy, 16B per lane. LDS dest is wave-uniform base +
    // lane*16 (hardware semantics); we pass the uniform row base.
    __builtin_amdgcn_global_load_lds(
        (const __attribute__((address_space(1))) void*)g,
        (__attribute__((address_space(3))) void*)lds, 16, 0, 0);
}

// ---- 100 named weight scalars: declaration, gather, FMA taps -------------
#define WDECL(R)                                                              \
    float w##R##_0, w##R##_1, w##R##_2, w##R##_3, w##R##_4, w##R##_5,         \
        w##R##_6, w##R##_7, w##R##_8, w##R##_9, w##R##_10, w##R##_11,         \
        w##R##_12, w##R##_13, w##R##_14, w##R##_15, w##R##_16, w##R##_17,     \
        w##R##_18, w##R##_19, w##R##_20, w##R##_21, w##R##_22, w##R##_23,     \
        w##R##_24;

#define WGATH(R)                                                              \
    {                                                                         \
        const float* wp = &sb[bkt##R * (KS * KS)];                            \
        w##R##_0 = wp[0];   w##R##_1 = wp[1];   w##R##_2 = wp[2];             \
        w##R##_3 = wp[3];   w##R##_4 = wp[4];   w##R##_5 = wp[5];             \
        w##R##_6 = wp[6];   w##R##_7 = wp[7];   w##R##_8 = wp[8];             \
        w##R##_9 = wp[9];   w##R##_10 = wp[10]; w##R##_11 = wp[11];           \
        w##R##_12 = wp[12]; w##R##_13 = wp[13]; w##R##_14 = wp[14];           \
        w##R##_15 = wp[15]; w##R##_16 = wp[16]; w##R##_17 = wp[17];           \
        w##R##_18 = wp[18]; w##R##_19 = wp[19]; w##R##_20 = wp[20];           \
        w##R##_21 = wp[21]; w##R##_22 = wp[22]; w##R##_23 = wp[23];           \
        w##R##_24 = wp[24];                                                   \
    }

#define F5(R, T0, T1, T2, T3, T4)                                             \
    acc##R += x0 * w##R##_##T0 + x1 * w##R##_##T1 + x2 * w##R##_##T2          \
            + x3 * w##R##_##T3 + x4 * w##R##_##T4;

#define K0(R) F5(R, 0, 1, 2, 3, 4)
#define K1(R) F5(R, 5, 6, 7, 8, 9)
#define K2(R) F5(R, 10, 11, 12, 13, 14)
#define K3(R) F5(R, 15, 16, 17, 18, 19)
#define K4(R) F5(R, 20, 21, 22, 23, 24)

#define LOADX(CUR, SLAB, I)                                                   \
    {                                                                         \
        const float* rp = &sin_[CUR][SLAB][ty4 + (I)][wcol + (LPAD - HALO)];  \
        x0 = rp[0]; x1 = rp[1]; x2 = rp[2]; x3 = rp[3]; x4 = rp[4];           \
    }

__global__ __launch_bounds__(NTHREADS, 3) void csconv_kernel(
    const float* __restrict__ in, const float* __restrict__ bank,
    const int* __restrict__ buckets, float* __restrict__ out)
{
    __shared__ float sb[NB * KS * KS];                    // 2.5 KB kernel bank
    __shared__ __align__(16) float sin_[2][2][LH][LROW];  // 37.5 KB: 2 bufs x 2 ch

    const int tid  = threadIdx.x;
    const int wcol = tid % WID;     // 0..191
    const int ty   = tid / WID;     // 0..1
    const int lane = tid & 63;
    const int wv   = tid >> 6;      // wave id 0..5
    const int cg   = blockIdx.x;    // channel group 0..3
    const int ht   = blockIdx.y;    // row tile 0..23
    const int b    = blockIdx.z;    // batch 0..7
    const int h0   = ht * TH;
    const int r0   = h0 + ty * RPT;

    const int c0 = cg * CPB;
    const float* inb  = in  + (size_t)(b * CH + c0) * HW;
    float*       outb = out + (size_t)(b * CH + c0) * HW;

    // --- one-time LDS init ---------------------------------------------
    // Kernel bank (625 floats > 384 threads: must be strided).
    for (int t = tid; t < NB * KS * KS; t += NTHREADS) sb[t] = bank[t];

    // Zero halo columns 0..3 and 196..199 of all 4 slabs (one write/thread:
    // 4 slabs * 12 rows * 8 cols = 384). Persist: staging writes cols 4..195.
    {
        const int s = tid / 96, rem = tid % 96;
        const int r = rem / 8, p = rem % 8;
        const int col = (p < 4) ? p : (WID + p);   // 0..3, 196..199
        sin_[s >> 1][s & 1][r][col] = 0.0f;
    }
    // Zero out-of-image rows for edge tiles; staging skips them so the
    // zeros persist for every channel.
    if (h0 - HALO < 0) {
        for (int t = tid; t < 4 * 2 * LROW; t += NTHREADS) {
            const int s = t / (2 * LROW), rem = t % (2 * LROW);
            sin_[s >> 1][s & 1][rem / LROW][rem % LROW] = 0.0f;
        }
    }
    if (h0 + TH + HALO > HEI) {
        for (int t = tid; t < 4 * 2 * LROW; t += NTHREADS) {
            const int s = t / (2 * LROW), rem = t % (2 * LROW);
            sin_[s >> 1][s & 1][LH - 2 + rem / LROW][rem % LROW] = 0.0f;
        }
    }

    // Prologue: async-stage channels 0,1 into buffer 0. Wave wv stages rows
    // 2wv, 2wv+1 of each slab; 48 lanes x 16B cover one 192-float row.
#pragma unroll
    for (int s = 0; s < 2; ++s)
#pragma unroll
        for (int k = 0; k < 2; ++k) {
            const int rr = 2 * wv + k;
            const int hg = h0 - HALO + rr;
            if (hg >= 0 && hg < HEI && lane < 48)
                async16(&sin_[0][s][rr][LPAD],
                        inb + (size_t)s * HW + (size_t)hg * WID + lane * 4);
        }

    __syncthreads();   // full drain once: bank, zeros, prologue copies

    // --- per-pixel weight gather: 4 buckets -> 100 named scalars ---------
    const int bkt0 = buckets[(b * HEI + r0 + 0) * WID + wcol];
    const int bkt1 = buckets[(b * HEI + r0 + 1) * WID + wcol];
    const int bkt2 = buckets[(b * HEI + r0 + 2) * WID + wcol];
    const int bkt3 = buckets[(b * HEI + r0 + 3) * WID + wcol];
    WDECL(0) WDECL(1) WDECL(2) WDECL(3)
    WGATH(0) WGATH(1) WGATH(2) WGATH(3)

    const int ty4 = ty * RPT;

    // Straight-line conv: staged row ty4+i = global row r0-2+i. Output row
    // r0+r consumes staged rows i=r..r+4 with kernel row ki=i-r.
#define CONV_STORE(CUR, SLAB, CIDX)                                           \
    {                                                                         \
        float acc0 = 0.0f, acc1 = 0.0f, acc2 = 0.0f, acc3 = 0.0f;             \
        float x0, x1, x2, x3, x4;                                             \
        LOADX(CUR, SLAB, 0) K0(0)                                             \
        LOADX(CUR, SLAB, 1) K1(0) K0(1)                                       \
        LOADX(CUR, SLAB, 2) K2(0) K1(1) K0(2)                                 \
        LOADX(CUR, SLAB, 3) K3(0) K2(1) K1(2) K0(3)                           \
        LOADX(CUR, SLAB, 4) K4(0) K3(1) K2(2) K1(3)                           \
        LOADX(CUR, SLAB, 5) K4(1) K3(2) K2(3)                                 \
        LOADX(CUR, SLAB, 6) K4(2) K3(3)                                       \
        LOADX(CUR, SLAB, 7) K4(3)                                             \
        float* op = outb + (size_t)(CIDX) * HW + (size_t)r0 * WID + wcol;     \
        op[0 * WID] = acc0; op[1 * WID] = acc1;                               \
        op[2 * WID] = acc2; op[3 * WID] = acc3;                               \
    }

    // --- main loop: 12 phases of 2 channels --------------------------------
    for (int c = 0; c < CPB; c += 2) {
        const int cur = (c >> 1) & 1;
        const bool has_next = (c + 2 < CPB);

        if (has_next) {
            const int nxt = cur ^ 1;
#pragma unroll
            for (int s = 0; s < 2; ++s)
#pragma unroll
                for (int k = 0; k < 2; ++k) {
                    const int rr = 2 * wv + k;
                    const int hg = h0 - HALO + rr;
                    if (hg >= 0 && hg < HEI && lane < 48)
                        async16(&sin_[nxt][s][rr][LPAD],
                                inb + (size_t)(c + 2 + s) * HW
                                    + (size_t)hg * WID + lane * 4);
                }
        }

        CONV_STORE(cur, 0, c)
        CONV_STORE(cur, 1, c + 1)

        if (has_next) {
            // Program order this phase: 4 async loads, then 8 stores.
            // vmcnt(8) retires (in-order) everything older than the 8 newest
            // VMEM ops -> exactly the loads; stores stay in flight.
            asm volatile("s_waitcnt vmcnt(8)" ::: "memory");
            __builtin_amdgcn_s_barrier();
            asm volatile("" ::: "memory");
        }
    }
}

extern "C" void kernel_launch(void* const* d_in, const int* in_sizes, int n_in,
                              void* d_out, int out_size, void* d_ws, size_t ws_size,
                              hipStream_t stream) {
    const float* in      = (const float*)d_in[0];
    const float* bank    = (const float*)d_in[1];
    const int*   buckets = (const int*)d_in[2];
    float*       out     = (float*)d_out;
    dim3 grid(CSPLIT, HEI / TH, NBATCH);
    csconv_kernel<<<grid, NTHREADS, 0, stream>>>(in, bank, buckets, out);
}

// Round 4
// 211.204 us; speedup vs baseline: 1.0744x; 1.0744x over previous
//
#include <hip/hip_runtime.h>

// CSConv2D: per-pixel kernel selection from a 25-entry 5x5 bank, depthwise,
// 'same' zero pad. B=8, C=96, H=W=192, fp32.
//
// R7: RPT 4 -> 2. Three rounds of evidence (R4 array / R5 asm-pin / R6 named
// scalars all at VGPR_Count 68-80, dur 91-99us) show the compiler refuses to
// keep a 100-float weight cache in arch VGPRs — it lands in scratch or AGPRs
// with a per-use access cost, regardless of phrasing. Stop fighting regalloc;
// shrink the working set: 2 output rows/thread -> 2 buckets -> 50 named
// scalar weights (~90 live total), which is holdable. Input LDS reads rise
// 10 -> 15 floats/output, but the ~25 weight re-reads/output disappear:
// net per-output memory ops ~35 -> ~15.
//
// Geometry: TH=8 rows/block kept (same 12-row staged slab, same halo ratio),
// 768 threads = 4 row-groups x 192 cols = 12 waves; 2 blocks/CU (thread-
// limited), 24 waves/CU. Staging via global_load_lds width=16 into
// 200-float padded rows; 2 channels/phase, 4 slabs; counted s_waitcnt
// vmcnt(4) before s_barrier (per wave: 2 async loads then 4 output stores;
// vmcnt(4) retires exactly the loads). Halo cols / OOB rows zeroed once.
//
// Decisive check next round: VGPR_Count ~90-110. If it collapses to ~70
// again, go to RPT=1 (25 weights).

#define KS 5
#define NB 25
#define HALO 2
#define TH 8                     // output rows per block
#define RPT 2                    // output rows per thread
#define WID 192
#define HEI 192
#define CH 96
#define NBATCH 8
#define LPAD 4                   // left pad so row data start is 16B-aligned
#define LROW (LPAD + WID + LPAD) // 200 floats per LDS row
#define LH (TH + 2 * HALO)       // 12 staged rows
#define CSPLIT 4
#define CPB (CH / CSPLIT)        // 24 channels per block
#define NTHREADS (WID * (TH / RPT))  // 768 threads = 12 waves
#define NWAVES (NTHREADS / 64)       // 12
#define HW ((size_t)HEI * WID)

static_assert(CPB % 2 == 0, "channel loop processes channel pairs");
static_assert(NTHREADS <= 1024, "block size limit");

__device__ __forceinline__ void async16(void* lds, const void* g) {
    // Direct global->LDS copy, 16B per lane. LDS dest is wave-uniform base +
    // lane*16 (hardware semantics); we pass the uniform row base.
    __builtin_amdgcn_global_load_lds(
        (const __attribute__((address_space(1))) void*)g,
        (__attribute__((address_space(3))) void*)lds, 16, 0, 0);
}

// ---- 50 named weight scalars: declaration, gather, FMA taps --------------
#define WDECL(R)                                                              \
    float w##R##_0, w##R##_1, w##R##_2, w##R##_3, w##R##_4, w##R##_5,         \
        w##R##_6, w##R##_7, w##R##_8, w##R##_9, w##R##_10, w##R##_11,         \
        w##R##_12, w##R##_13, w##R##_14, w##R##_15, w##R##_16, w##R##_17,     \
        w##R##_18, w##R##_19, w##R##_20, w##R##_21, w##R##_22, w##R##_23,     \
        w##R##_24;

#define WGATH(R)                                                              \
    {                                                                         \
        const float* wp = &sb[bkt##R * (KS * KS)];                            \
        w##R##_0 = wp[0];   w##R##_1 = wp[1];   w##R##_2 = wp[2];             \
        w##R##_3 = wp[3];   w##R##_4 = wp[4];   w##R##_5 = wp[5];             \
        w##R##_6 = wp[6];   w##R##_7 = wp[7];   w##R##_8 = wp[8];             \
        w##R##_9 = wp[9];   w##R##_10 = wp[10]; w##R##_11 = wp[11];           \
        w##R##_12 = wp[12]; w##R##_13 = wp[13]; w##R##_14 = wp[14];           \
        w##R##_15 = wp[15]; w##R##_16 = wp[16]; w##R##_17 = wp[17];           \
        w##R##_18 = wp[18]; w##R##_19 = wp[19]; w##R##_20 = wp[20];           \
        w##R##_21 = wp[21]; w##R##_22 = wp[22]; w##R##_23 = wp[23];           \
        w##R##_24 = wp[24];                                                   \
    }

#define F5(R, T0, T1, T2, T3, T4)                                             \
    acc##R += x0 * w##R##_##T0 + x1 * w##R##_##T1 + x2 * w##R##_##T2          \
            + x3 * w##R##_##T3 + x4 * w##R##_##T4;

#define K0(R) F5(R, 0, 1, 2, 3, 4)
#define K1(R) F5(R, 5, 6, 7, 8, 9)
#define K2(R) F5(R, 10, 11, 12, 13, 14)
#define K3(R) F5(R, 15, 16, 17, 18, 19)
#define K4(R) F5(R, 20, 21, 22, 23, 24)

#define LOADX(CUR, SLAB, I)                                                   \
    {                                                                         \
        const float* rp = &sin_[CUR][SLAB][ty2 + (I)][wcol + (LPAD - HALO)];  \
        x0 = rp[0]; x1 = rp[1]; x2 = rp[2]; x3 = rp[3]; x4 = rp[4];           \
    }

__global__ __launch_bounds__(NTHREADS, 2) void csconv_kernel(
    const float* __restrict__ in, const float* __restrict__ bank,
    const int* __restrict__ buckets, float* __restrict__ out)
{
    __shared__ float sb[NB * KS * KS];                    // 2.5 KB kernel bank
    __shared__ __align__(16) float sin_[2][2][LH][LROW];  // 37.5 KB: 2 bufs x 2 ch

    const int tid  = threadIdx.x;
    const int wcol = tid % WID;     // 0..191
    const int ty   = tid / WID;     // 0..3 (row group)
    const int lane = tid & 63;
    const int wv   = tid >> 6;      // wave id 0..11
    const int cg   = blockIdx.x;    // channel group 0..3
    const int ht   = blockIdx.y;    // row tile 0..23
    const int b    = blockIdx.z;    // batch 0..7
    const int h0   = ht * TH;
    const int r0   = h0 + ty * RPT; // first output row this thread owns

    const int c0 = cg * CPB;
    const float* inb  = in  + (size_t)(b * CH + c0) * HW;
    float*       outb = out + (size_t)(b * CH + c0) * HW;

    // --- one-time LDS init ---------------------------------------------
    // Kernel bank: 625 floats, 768 threads -> single shot.
    if (tid < NB * KS * KS) sb[tid] = bank[tid];

    // Zero halo columns 0..3 and 196..199 of all 4 slabs (384 writes).
    // Persist: staging only writes cols 4..195 of in-bounds rows.
    if (tid < 4 * LH * 8) {
        const int s = tid / 96, rem = tid % 96;
        const int r = rem / 8, p = rem % 8;
        const int col = (p < 4) ? p : (WID + p);   // 0..3, 196..199
        sin_[s >> 1][s & 1][r][col] = 0.0f;
    }
    // Zero out-of-image rows for edge tiles; staging skips them so the
    // zeros persist for every channel.
    if (h0 - HALO < 0) {
        for (int t = tid; t < 4 * 2 * LROW; t += NTHREADS) {
            const int s = t / (2 * LROW), rem = t % (2 * LROW);
            sin_[s >> 1][s & 1][rem / LROW][rem % LROW] = 0.0f;
        }
    }
    if (h0 + TH + HALO > HEI) {
        for (int t = tid; t < 4 * 2 * LROW; t += NTHREADS) {
            const int s = t / (2 * LROW), rem = t % (2 * LROW);
            sin_[s >> 1][s & 1][LH - 2 + rem / LROW][rem % LROW] = 0.0f;
        }
    }

    // Prologue: async-stage channels 0,1 into buffer 0. 24 row-copies
    // (2 slabs x 12 rows); wave wv does copies 2wv, 2wv+1. 48 lanes x 16B
    // cover one 192-float row.
#pragma unroll
    for (int k = 0; k < 2; ++k) {
        const int m  = 2 * wv + k;        // 0..23
        const int s  = m / LH;            // slab (channel) 0..1
        const int rr = m % LH;            // staged row 0..11
        const int hg = h0 - HALO + rr;
        if (hg >= 0 && hg < HEI && lane < 48)
            async16(&sin_[0][s][rr][LPAD],
                    inb + (size_t)s * HW + (size_t)hg * WID + lane * 4);
    }

    __syncthreads();   // full drain once: bank, zeros, prologue copies

    // --- per-pixel weight gather: 2 buckets -> 50 named scalars ----------
    const int bkt0 = buckets[(b * HEI + r0 + 0) * WID + wcol];
    const int bkt1 = buckets[(b * HEI + r0 + 1) * WID + wcol];
    WDECL(0) WDECL(1)
    WGATH(0) WGATH(1)

    const int ty2 = ty * RPT;

    // Straight-line conv: staged row ty2+i = global row r0-2+i. Output row
    // r0+r consumes staged rows i=r..r+4 with kernel row ki=i-r.
#define CONV_STORE(CUR, SLAB, CIDX)                                           \
    {                                                                         \
        float acc0 = 0.0f, acc1 = 0.0f;                                       \
        float x0, x1, x2, x3, x4;                                             \
        LOADX(CUR, SLAB, 0) K0(0)                                             \
        LOADX(CUR, SLAB, 1) K1(0) K0(1)                                       \
        LOADX(CUR, SLAB, 2) K2(0) K1(1)                                       \
        LOADX(CUR, SLAB, 3) K3(0) K2(1)                                       \
        LOADX(CUR, SLAB, 4) K4(0) K3(1)                                       \
        LOADX(CUR, SLAB, 5) K4(1)                                             \
        float* op = outb + (size_t)(CIDX) * HW + (size_t)r0 * WID + wcol;     \
        op[0 * WID] = acc0; op[1 * WID] = acc1;                               \
    }

    // --- main loop: 12 phases of 2 channels --------------------------------
    for (int c = 0; c < CPB; c += 2) {
        const int cur = (c >> 1) & 1;
        const bool has_next = (c + 2 < CPB);

        if (has_next) {
            const int nxt = cur ^ 1;
#pragma unroll
            for (int k = 0; k < 2; ++k) {
                const int m  = 2 * wv + k;
                const int s  = m / LH;
                const int rr = m % LH;
                const int hg = h0 - HALO + rr;
                if (hg >= 0 && hg < HEI && lane < 48)
                    async16(&sin_[nxt][s][rr][LPAD],
                            inb + (size_t)(c + 2 + s) * HW
                                + (size_t)hg * WID + lane * 4);
            }
        }

        CONV_STORE(cur, 0, c)
        CONV_STORE(cur, 1, c + 1)

        if (has_next) {
            // Program order this phase (per wave): 2 async loads, then 4
            // output stores. vmcnt(4) retires (in-order) everything older
            // than the 4 newest VMEM ops -> exactly the loads; the output
            // stores stay in flight across the barrier.
            asm volatile("s_waitcnt vmcnt(4)" ::: "memory");
            __builtin_amdgcn_s_barrier();
            asm volatile("" ::: "memory");
        }
    }
}

extern "C" void kernel_launch(void* const* d_in, const int* in_sizes, int n_in,
                              void* d_out, int out_size, void* d_ws, size_t ws_size,
                              hipStream_t stream) {
    const float* in      = (const float*)d_in[0];
    const float* bank    = (const float*)d_in[1];
    const int*   buckets = (const int*)d_in[2];
    float*       out     = (float*)d_out;
    dim3 grid(CSPLIT, HEI / TH, NBATCH);
    csconv_kernel<<<grid, NTHREADS, 0, stream>>>(in, bank, buckets, out);
}